// Round 1
// baseline (80.018 us; speedup 1.0000x reference)
//
#include <hip/hip_runtime.h>
#include <math.h>

// Problem constants: B=8, S=4096, D=1024, Q=16 -> 32768 rows
#define ROWS_TOTAL 32768
#define DDIM 1024
#define QDIM 16

// ============================================================
// Kernel Z: z[row][q] = cos(relu(x[row]@W1 + b1) + theta)
//   Read-streaming kernel. Same mm1 structure as the fused kernel
//   (reg-resident W1, 3-stage butterfly, 16 LDS contributors, ONE
//   barrier per 4-row phase) but with no mm2/W2/zs coupling.
//   A rotating finisher wave (wid==ph) does the 16-way sum + cos +
//   64B z store, so the other 7 waves stream straight into the next
//   phase's prefetch+mm1.
// ============================================================
#define ZTPB 512
#define ZR 4                      // rows per phase
#define ZRPB 16                   // rows per block
#define ZNPH (ZRPB / ZR)          // 4 phases
#define ZNBLOCKS (ROWS_TOTAL / ZRPB)  // 2048

__global__ __launch_bounds__(ZTPB, 4)
void z_kernel(const float* __restrict__ x, const float* __restrict__ W1,
              const float* __restrict__ b1, const float* __restrict__ theta,
              float* __restrict__ z, int zstride) {
  const int t    = threadIdx.x;
  const int lane = t & 63;
  const int wid  = t >> 6;
  const int qg   = t & 3;     // mm1: 4 q's = 4qg..4qg+3
  const int c    = t >> 2;    // mm1: k-chunk of 8 at 8c  (c in [0,128))
  const int q5   = lane & 15; // finisher: this lane's q
  const int r5   = lane >> 4; // finisher: this lane's row-in-phase

  __shared__ __align__(16) float hw[2][16][ZR][QDIM];  // [buf][contrib][r][q]

  // W1 register-resident: W1[8c+j][4qg+i]  (block holds W1 exactly once)
  float w1r[8][4];
  {
    const float* p = W1 + (size_t)(8 * c) * QDIM + 4 * qg;
#pragma unroll
    for (int j = 0; j < 8; ++j) {
      float4 v = *reinterpret_cast<const float4*>(p + (size_t)j * QDIM);
      w1r[j][0] = v.x; w1r[j][1] = v.y; w1r[j][2] = v.z; w1r[j][3] = v.w;
    }
  }
  const float b1q = b1[q5];
  const float thq = theta[q5];

  const int row0 = blockIdx.x * ZRPB;

  // x registers for the current phase's 4 rows (8 floats each)
  float4 xa[ZR], xb[ZR];
  {
    const float* p = x + (size_t)row0 * DDIM + 8 * c;
#pragma unroll
    for (int r = 0; r < ZR; ++r) {
      xa[r] = *reinterpret_cast<const float4*>(p + (size_t)r * DDIM);
      xb[r] = *reinterpret_cast<const float4*>(p + (size_t)r * DDIM + 4);
    }
  }

  for (int ph = 0; ph < ZNPH; ++ph) {
    const int buf = ph & 1;

    // ---- mm1: 4 rows x 4 q partials over this thread's 8 k's
    float hp[ZR][4];
#pragma unroll
    for (int r = 0; r < ZR; ++r) {
      const float xv[8] = {xa[r].x, xa[r].y, xa[r].z, xa[r].w,
                           xb[r].x, xb[r].y, xb[r].z, xb[r].w};
      float h0 = 0.f, h1 = 0.f, h2 = 0.f, h3 = 0.f;
#pragma unroll
      for (int j = 0; j < 8; ++j) {
        h0 = fmaf(xv[j], w1r[j][0], h0);
        h1 = fmaf(xv[j], w1r[j][1], h1);
        h2 = fmaf(xv[j], w1r[j][2], h2);
        h3 = fmaf(xv[j], w1r[j][3], h3);
      }
      hp[r][0] = h0; hp[r][1] = h1; hp[r][2] = h2; hp[r][3] = h3;
    }

    // ---- 3-stage butterfly (reduces lane bits 2..4 -> 2 holders/wave)
#pragma unroll
    for (int m = 4; m <= 16; m <<= 1)
#pragma unroll
      for (int r = 0; r < ZR; ++r)
#pragma unroll
        for (int qq = 0; qq < 4; ++qq)
          hp[r][qq] += __shfl_xor(hp[r][qq], m, 64);

    // holders: lanes {0..3, 32..35} per wave -> 16 contributors per block
    if ((lane & 28) == 0) {
      const int j = wid * 2 + (lane >> 5);
#pragma unroll
      for (int r = 0; r < ZR; ++r)
        *reinterpret_cast<float4*>(&hw[buf][j][r][4 * qg]) =
            make_float4(hp[r][0], hp[r][1], hp[r][2], hp[r][3]);
    }
    __syncthreads();  // the ONLY barrier in the phase

    // ---- prefetch next phase's x (issue before the finisher work)
    if (ph + 1 < ZNPH) {
      const float* p = x + (size_t)(row0 + (ph + 1) * ZR) * DDIM + 8 * c;
#pragma unroll
      for (int r = 0; r < ZR; ++r) {
        xa[r] = *reinterpret_cast<const float4*>(p + (size_t)r * DDIM);
        xb[r] = *reinterpret_cast<const float4*>(p + (size_t)r * DDIM + 4);
      }
    }

    // ---- finisher (rotating wave): 16-way sum + cos + 64B z store.
    // Safe with the [2] hw double-buffer: phase ph+2 rewrites this buf
    // only after barrier(ph+1), which the finisher can't pass before
    // completing this block (program order).
    if (wid == ph) {
      float s = 0.f;
#pragma unroll
      for (int j = 0; j < 16; ++j) s += hw[buf][j][r5][q5];
      s = fmaxf(s + b1q, 0.f) + thq;
      z[(size_t)(row0 + ph * ZR + r5) * zstride + q5] = __cosf(s);
    }
  }
}

// ============================================================
// Kernel O: out[row] = z[row] @ W2 + b2
//   Pure write-streaming: no barriers, no LDS, no shuffles.
//   W2 register-resident (16 x float4 per thread), z row loaded via
//   wave-uniform loads with a one-row prefetch, float4 stores.
//   z/out intentionally NOT __restrict__: in the workspace-too-small
//   fallback, z aliases out[row][0:16]; the prefetch-then-store order
//   inside each iteration keeps that correct.
// ============================================================
#define OTPB 256
#define ORPB 16
#define ONBLOCKS (ROWS_TOTAL / ORPB)  // 2048

__global__ __launch_bounds__(OTPB, 4)
void o_kernel(const float* z, int zstride, const float* __restrict__ W2,
              const float* __restrict__ b2, float* out) {
  const int t   = threadIdx.x;
  const int col = 4 * t;  // this thread's 4 output columns

  // W2 register-resident: W2[q][col..col+3]  (block holds W2 exactly once)
  float4 w2r[QDIM];
#pragma unroll
  for (int q = 0; q < QDIM; ++q)
    w2r[q] = *reinterpret_cast<const float4*>(W2 + (size_t)q * DDIM + col);
  const float4 bb = *reinterpret_cast<const float4*>(b2 + col);

  const int row0 = blockIdx.x * ORPB;

  // current row's z (wave-uniform address -> scalar-path loads)
  const float* zp0 = z + (size_t)row0 * zstride;
  float4 zc0 = *reinterpret_cast<const float4*>(zp0 + 0);
  float4 zc1 = *reinterpret_cast<const float4*>(zp0 + 4);
  float4 zc2 = *reinterpret_cast<const float4*>(zp0 + 8);
  float4 zc3 = *reinterpret_cast<const float4*>(zp0 + 12);

#pragma unroll
  for (int r = 0; r < ORPB; ++r) {
    // prefetch next row's z BEFORE storing this row (also makes the
    // aliased fallback correct: read row r+1 precedes store of row r)
    float4 zn0 = zc0, zn1 = zc1, zn2 = zc2, zn3 = zc3;
    if (r + 1 < ORPB) {
      const float* znp = z + (size_t)(row0 + r + 1) * zstride;
      zn0 = *reinterpret_cast<const float4*>(znp + 0);
      zn1 = *reinterpret_cast<const float4*>(znp + 4);
      zn2 = *reinterpret_cast<const float4*>(znp + 8);
      zn3 = *reinterpret_cast<const float4*>(znp + 12);
    }

    const float zv[16] = {zc0.x, zc0.y, zc0.z, zc0.w,
                          zc1.x, zc1.y, zc1.z, zc1.w,
                          zc2.x, zc2.y, zc2.z, zc2.w,
                          zc3.x, zc3.y, zc3.z, zc3.w};
    float4 acc = bb;
#pragma unroll
    for (int q = 0; q < QDIM; ++q) {
      acc.x = fmaf(zv[q], w2r[q].x, acc.x);
      acc.y = fmaf(zv[q], w2r[q].y, acc.y);
      acc.z = fmaf(zv[q], w2r[q].z, acc.z);
      acc.w = fmaf(zv[q], w2r[q].w, acc.w);
    }
    *reinterpret_cast<float4*>(out + (size_t)(row0 + r) * DDIM + col) = acc;

    zc0 = zn0; zc1 = zn1; zc2 = zn2; zc3 = zn3;
  }
}

extern "C" void kernel_launch(void* const* d_in, const int* in_sizes, int n_in,
                              void* d_out, int out_size, void* d_ws, size_t ws_size,
                              hipStream_t stream) {
  const float* x     = (const float*)d_in[0];
  const float* W1    = (const float*)d_in[1];
  const float* b1    = (const float*)d_in[2];
  const float* theta = (const float*)d_in[3];
  const float* W2    = (const float*)d_in[4];
  const float* b2    = (const float*)d_in[5];
  float* out = (float*)d_out;

  const size_t zbytes = (size_t)ROWS_TOTAL * QDIM * sizeof(float);  // 2 MB
  float* zbuf;
  int zstride;
  if (d_ws != nullptr && ws_size >= zbytes) {
    zbuf = (float*)d_ws;  // compact z in workspace
    zstride = QDIM;
  } else {
    zbuf = out;           // fallback: stash z in out[row][0:16]
    zstride = DDIM;
  }

  z_kernel<<<dim3(ZNBLOCKS), dim3(ZTPB), 0, stream>>>(x, W1, b1, theta, zbuf, zstride);
  o_kernel<<<dim3(ONBLOCKS), dim3(OTPB), 0, stream>>>(zbuf, zstride, W2, b2, out);
}

// Round 2
// 78.235 us; speedup vs baseline: 1.0228x; 1.0228x over previous
//
#include <hip/hip_runtime.h>
#include <math.h>

// Problem constants: B=8, S=4096, D=1024, Q=16 -> 32768 rows
#define ROWS_TOTAL 32768
#define DDIM 1024
#define QDIM 16

// ============================================================
// Kernel Z: z[row][q] = cos(relu(x[row]@W1 + b1) + theta)
//
// Structure: 512 threads, 16 rows/block, 2 rows/phase, 8 phases.
// Thread (c = t>>2, qg = t&3) owns x-chunk d=[8c,8c+8) and q-group
// [4qg,4qg+4); W1 register-resident (block holds W1 exactly once).
// Per phase: mm1 -> issue prefetch(ph+2) -> 3-stage butterfly ->
// 16 holder lanes write LDS -> lgkmcnt(0) + RAW s_barrier (vmcnt NOT
// drained -> x prefetch stays in flight across the barrier; compiler
// emits a counted vmcnt before the next mm1's register use) ->
// rotating finisher wave (wid==ph) sums 16 contributions (split 8+8
// across half-waves + shfl_xor(32)), cos, 128B z store.
//
// x double-buffer is TWO NAMED register arrays (xA/xB) with static
// indexing only (runtime-indexed reg arrays go to scratch).
// ============================================================
#define ZTPB 512
#define ZR 2                       // rows per phase
#define ZRPB 16                    // rows per block
#define ZNPH (ZRPB / ZR)           // 8 phases
#define ZNBLOCKS (ROWS_TOTAL / ZRPB)   // 2048

__global__ __launch_bounds__(ZTPB, 4)
void z_kernel(const float* __restrict__ x, const float* __restrict__ W1,
              const float* __restrict__ b1, const float* __restrict__ theta,
              float* __restrict__ z, int zstride) {
  const int t    = threadIdx.x;
  const int lane = t & 63;
  const int wid  = t >> 6;
  const int qg   = t & 3;     // mm1: 4 q's = 4qg..4qg+3
  const int c    = t >> 2;    // mm1: k-chunk of 8 at 8c  (c in [0,128))

  __shared__ __align__(16) float hw[2][16][ZR][QDIM];  // [buf][contrib][r][q]

  // W1 register-resident: W1[8c+j][4qg+i]
  float w1r[8][4];
  {
    const float* p = W1 + (size_t)(8 * c) * QDIM + 4 * qg;
#pragma unroll
    for (int j = 0; j < 8; ++j) {
      float4 v = *reinterpret_cast<const float4*>(p + (size_t)j * QDIM);
      w1r[j][0] = v.x; w1r[j][1] = v.y; w1r[j][2] = v.z; w1r[j][3] = v.w;
    }
  }
  const float b1q = b1[lane & 15];
  const float thq = theta[lane & 15];

  const int row0 = blockIdx.x * ZRPB;
  const float* xrow = x + (size_t)row0 * DDIM + 8 * c;

  // -------- depth-2 x double buffer: xA = even phases, xB = odd phases
  float4 xA[ZR][2], xB[ZR][2];
#pragma unroll
  for (int r = 0; r < ZR; ++r) {
    xA[r][0] = *reinterpret_cast<const float4*>(xrow + (size_t)r * DDIM);
    xA[r][1] = *reinterpret_cast<const float4*>(xrow + (size_t)r * DDIM + 4);
  }
#pragma unroll
  for (int r = 0; r < ZR; ++r) {
    xB[r][0] = *reinterpret_cast<const float4*>(xrow + (size_t)(ZR + r) * DDIM);
    xB[r][1] = *reinterpret_cast<const float4*>(xrow + (size_t)(ZR + r) * DDIM + 4);
  }
  asm volatile("" ::: "memory");  // pin prologue loads here

  // One phase. cur = this phase's x buffer; it is refilled with phase
  // ph+2's rows immediately after mm1 consumes it (WAR is safe: loads
  // issued after the reads, in-order issue).
  auto phase = [&](int ph, float4 (&cur)[ZR][2]) {
    const int buf = ph & 1;

    // ---- mm1: ZR rows x 4 q partials over this thread's 8 k's
    float hp[ZR][4];
#pragma unroll
    for (int r = 0; r < ZR; ++r) {
      const float xv[8] = {cur[r][0].x, cur[r][0].y, cur[r][0].z, cur[r][0].w,
                           cur[r][1].x, cur[r][1].y, cur[r][1].z, cur[r][1].w};
      float h0 = 0.f, h1 = 0.f, h2 = 0.f, h3 = 0.f;
#pragma unroll
      for (int j = 0; j < 8; ++j) {
        h0 = fmaf(xv[j], w1r[j][0], h0);
        h1 = fmaf(xv[j], w1r[j][1], h1);
        h2 = fmaf(xv[j], w1r[j][2], h2);
        h3 = fmaf(xv[j], w1r[j][3], h3);
      }
      hp[r][0] = h0; hp[r][1] = h1; hp[r][2] = h2; hp[r][3] = h3;
    }

    // ---- issue prefetch for phase ph+2 into the buffer just consumed
    if (ph + 2 < ZNPH) {
      const float* p = xrow + (size_t)(ph + 2) * (ZR * DDIM);
#pragma unroll
      for (int r = 0; r < ZR; ++r) {
        cur[r][0] = *reinterpret_cast<const float4*>(p + (size_t)r * DDIM);
        cur[r][1] = *reinterpret_cast<const float4*>(p + (size_t)r * DDIM + 4);
      }
    }
    asm volatile("" ::: "memory");  // don't sink the prefetch below

    // ---- 3-stage butterfly (stays within 32-lane halves -> ds_swizzle)
#pragma unroll
    for (int m = 4; m <= 16; m <<= 1)
#pragma unroll
      for (int r = 0; r < ZR; ++r)
#pragma unroll
        for (int qq = 0; qq < 4; ++qq)
          hp[r][qq] += __shfl_xor(hp[r][qq], m, 64);

    // holders: lanes {0..3, 32..35} per wave -> 16 contributors per block
    if ((lane & 28) == 0) {
      const int j = wid * 2 + (lane >> 5);
#pragma unroll
      for (int r = 0; r < ZR; ++r)
        *reinterpret_cast<float4*>(&hw[buf][j][r][4 * qg]) =
            make_float4(hp[r][0], hp[r][1], hp[r][2], hp[r][3]);
    }

    // ---- RAW barrier: wait only LDS (lgkm), leave x loads in flight
    asm volatile("s_waitcnt lgkmcnt(0)" ::: "memory");
    __builtin_amdgcn_s_barrier();

    // ---- rotating finisher wave: 16-way sum split 8+8 across halves
    if (wid == ph) {
      const int q5 = lane & 15;
      const int r5 = (lane >> 4) & 1;
      const int jh = (lane >> 5) * 8;  // 0 or 8
      float s = 0.f;
#pragma unroll
      for (int j = 0; j < 8; ++j) s += hw[buf][jh + j][r5][q5];
      s += __shfl_xor(s, 32, 64);
      if (lane < 32) {
        s = fmaxf(s + b1q, 0.f) + thq;
        z[(size_t)(row0 + ph * ZR + r5) * zstride + q5] = __cosf(s);
      }
    }
  };

  for (int ph2 = 0; ph2 < ZNPH / 2; ++ph2) {
    phase(2 * ph2,     xA);
    phase(2 * ph2 + 1, xB);
  }
}

// ============================================================
// Kernel O: out[row] = z[row] @ W2 + b2
//   Pure write-streaming: no barriers, no LDS, no shuffles. Stores land
//   in L3 (128 MB < 256 MB) -> runs in a few us. Unchanged.
//   z/out intentionally NOT __restrict__ (aliased fallback).
// ============================================================
#define OTPB 256
#define ORPB 16
#define ONBLOCKS (ROWS_TOTAL / ORPB)  // 2048

__global__ __launch_bounds__(OTPB, 4)
void o_kernel(const float* z, int zstride, const float* __restrict__ W2,
              const float* __restrict__ b2, float* out) {
  const int t   = threadIdx.x;
  const int col = 4 * t;

  float4 w2r[QDIM];
#pragma unroll
  for (int q = 0; q < QDIM; ++q)
    w2r[q] = *reinterpret_cast<const float4*>(W2 + (size_t)q * DDIM + col);
  const float4 bb = *reinterpret_cast<const float4*>(b2 + col);

  const int row0 = blockIdx.x * ORPB;

  const float* zp0 = z + (size_t)row0 * zstride;
  float4 zc0 = *reinterpret_cast<const float4*>(zp0 + 0);
  float4 zc1 = *reinterpret_cast<const float4*>(zp0 + 4);
  float4 zc2 = *reinterpret_cast<const float4*>(zp0 + 8);
  float4 zc3 = *reinterpret_cast<const float4*>(zp0 + 12);

#pragma unroll
  for (int r = 0; r < ORPB; ++r) {
    float4 zn0 = zc0, zn1 = zc1, zn2 = zc2, zn3 = zc3;
    if (r + 1 < ORPB) {
      const float* znp = z + (size_t)(row0 + r + 1) * zstride;
      zn0 = *reinterpret_cast<const float4*>(znp + 0);
      zn1 = *reinterpret_cast<const float4*>(znp + 4);
      zn2 = *reinterpret_cast<const float4*>(znp + 8);
      zn3 = *reinterpret_cast<const float4*>(znp + 12);
    }

    const float zv[16] = {zc0.x, zc0.y, zc0.z, zc0.w,
                          zc1.x, zc1.y, zc1.z, zc1.w,
                          zc2.x, zc2.y, zc2.z, zc2.w,
                          zc3.x, zc3.y, zc3.z, zc3.w};
    float4 acc = bb;
#pragma unroll
    for (int q = 0; q < QDIM; ++q) {
      acc.x = fmaf(zv[q], w2r[q].x, acc.x);
      acc.y = fmaf(zv[q], w2r[q].y, acc.y);
      acc.z = fmaf(zv[q], w2r[q].z, acc.z);
      acc.w = fmaf(zv[q], w2r[q].w, acc.w);
    }
    *reinterpret_cast<float4*>(out + (size_t)(row0 + r) * DDIM + col) = acc;

    zc0 = zn0; zc1 = zn1; zc2 = zn2; zc3 = zn3;
  }
}

extern "C" void kernel_launch(void* const* d_in, const int* in_sizes, int n_in,
                              void* d_out, int out_size, void* d_ws, size_t ws_size,
                              hipStream_t stream) {
  const float* x     = (const float*)d_in[0];
  const float* W1    = (const float*)d_in[1];
  const float* b1    = (const float*)d_in[2];
  const float* theta = (const float*)d_in[3];
  const float* W2    = (const float*)d_in[4];
  const float* b2    = (const float*)d_in[5];
  float* out = (float*)d_out;

  const size_t zbytes = (size_t)ROWS_TOTAL * QDIM * sizeof(float);  // 2 MB
  float* zbuf;
  int zstride;
  if (d_ws != nullptr && ws_size >= zbytes) {
    zbuf = (float*)d_ws;  // compact z in workspace
    zstride = QDIM;
  } else {
    zbuf = out;           // fallback: stash z in out[row][0:16]
    zstride = DDIM;
  }

  z_kernel<<<dim3(ZNBLOCKS), dim3(ZTPB), 0, stream>>>(x, W1, b1, theta, zbuf, zstride);
  o_kernel<<<dim3(ONBLOCKS), dim3(OTPB), 0, stream>>>(zbuf, zstride, W2, b2, out);
}

// Round 4
// 55.933 us; speedup vs baseline: 1.4306x; 1.3987x over previous
//
#include <hip/hip_runtime.h>
#include <math.h>
#include <stdint.h>

// Problem constants: B=8, S=4096, D=1024, Q=16 -> 32768 rows
#define ROWS_TOTAL 32768
#define DDIM 1024
#define QDIM 16

typedef __attribute__((ext_vector_type(8))) short bf16x8;  // 8 bf16 (4 VGPRs)
typedef __attribute__((ext_vector_type(4))) float f32x4;   // 4 f32 acc

union ABfrag { uint32_t u[4]; bf16x8 v; };

// pack the high 16 bits (truncated bf16) of two f32 bit patterns:
// result low ushort = a.hi16 (lower-k element), high ushort = b.hi16
__device__ __forceinline__ uint32_t packhi(uint32_t a, uint32_t b) {
  return __builtin_amdgcn_perm(b, a, 0x07060302u);
}

// ============================================================
// Kernel Z (MFMA): z[row][q] = cos(relu(x[row]@W1 + b1) + theta)
//
// One wave owns 16 rows. K-loop: 32 steps of K=32 via
// __builtin_amdgcn_mfma_f32_16x16x32_bf16 (builtin -> compiler handles
// MFMA hazards/waitcnts; round-3 inline-asm version hit exactly that).
//
// f32 accuracy via split-bf16: f = hi + lo (truncation split), and
//   acc += A_hi*B_hi + A_lo*B_hi + A_hi*B_lo  (lo*lo ~2^-16 rel, dropped)
//
// A-frag: lane l holds x[row0+(l&15)][32s + (l>>4)*8 + j], j=0..7,
// loaded as 2 float4/lane and split in-register. B-frag: W1 pre-split
// and staged once per block into LDS in the SAME (l>>4)*8+j k-order.
// Even if hardware's true intra-lane k-order differs, a COMMON
// permutation of A and B k-slots leaves the contraction invariant.
// C/D layout (m89-verified): lane l holds D[(l>>4)*4+i][l&15].
//
// No barriers after the single staging barrier; depth-6 rotating
// prefetch (12 float4 in flight/lane) -> BW-bound streaming.
// ============================================================
#define ZTPB 256
#define ZWPB 4                      // waves per block
#define ZNBLOCKS (ROWS_TOTAL / (ZWPB * 16))   // 512

__global__ __launch_bounds__(ZTPB, 2)
void z_kernel(const float* __restrict__ x, const float* __restrict__ W1,
              const float* __restrict__ b1, const float* __restrict__ theta,
              float* __restrict__ z, int zstride) {
  const int t    = threadIdx.x;
  const int lane = t & 63;
  const int wid  = t >> 6;

  __shared__ __align__(16) ushort w1hi[32][64][8];  // [kstep][lane][j] 32 KB
  __shared__ __align__(16) ushort w1lo[32][64][8];  // 32 KB

  // ---------- stage W1 as split-bf16 B-fragments (once per block) ----------
  // Thread t owns W1 rows d = 4t..4t+3 (one 8-row j-block: shared step,
  // lane-group lg, j-half j0).
  {
    const int step = t >> 3;          // k-step = d/32
    const int lg   = (t >> 1) & 3;    // (d&31)>>3
    const int j0   = (t & 1) * 4;     // d&7 base
    const float* wp = W1 + (size_t)(4 * t) * QDIM;
    float4 wr[4][4];  // [row r][q-group]
#pragma unroll
    for (int r = 0; r < 4; ++r)
#pragma unroll
      for (int qq = 0; qq < 4; ++qq)
        wr[r][qq] =
            *reinterpret_cast<const float4*>(wp + (size_t)r * QDIM + 4 * qq);

#pragma unroll
    for (int qq = 0; qq < 4; ++qq) {
#pragma unroll
      for (int m = 0; m < 4; ++m) {
        const int q = 4 * qq + m;
        float f[4];
#pragma unroll
        for (int r = 0; r < 4; ++r)
          f[r] = (m == 0) ? wr[r][qq].x
               : (m == 1) ? wr[r][qq].y
               : (m == 2) ? wr[r][qq].z
                          : wr[r][qq].w;
        uint32_t u[4], l[4];
#pragma unroll
        for (int r = 0; r < 4; ++r) {
          u[r] = __float_as_uint(f[r]);
          l[r] = __float_as_uint(f[r] - __uint_as_float(u[r] & 0xFFFF0000u));
        }
        const int ln = lg * 16 + q;
        *reinterpret_cast<uint2*>(&w1hi[step][ln][j0]) =
            make_uint2(packhi(u[0], u[1]), packhi(u[2], u[3]));
        *reinterpret_cast<uint2*>(&w1lo[step][ln][j0]) =
            make_uint2(packhi(l[0], l[1]), packhi(l[2], l[3]));
      }
    }
  }

  // per-lane epilogue constants (issued early, used after the K-loop)
  const int   q5 = lane & 15;
  const float bq = b1[q5];
  const float tq = theta[q5];

  __syncthreads();

  // ---------- main: one 16-row tile per wave ----------
  const int row0 = (blockIdx.x * ZWPB + wid) * 16;
  const float* xl =
      x + (size_t)(row0 + (lane & 15)) * DDIM + (lane >> 4) * 8;

  // depth-6 rotating prefetch of A (raw f32)
  float4 pa[6], pb[6];
#pragma unroll
  for (int s = 0; s < 6; ++s) {
    pa[s] = *reinterpret_cast<const float4*>(xl + s * 32);
    pb[s] = *reinterpret_cast<const float4*>(xl + s * 32 + 4);
  }

  f32x4 acc = {0.f, 0.f, 0.f, 0.f};

#pragma unroll
  for (int s = 0; s < 32; ++s) {
    const float4 a0 = pa[s % 6];
    const float4 a1 = pb[s % 6];
    if (s + 6 < 32) {
      pa[s % 6] = *reinterpret_cast<const float4*>(xl + (s + 6) * 32);
      pb[s % 6] = *reinterpret_cast<const float4*>(xl + (s + 6) * 32 + 4);
    }

    const float fv[8] = {a0.x, a0.y, a0.z, a0.w, a1.x, a1.y, a1.z, a1.w};
    uint32_t u[8], l[8];
#pragma unroll
    for (int j = 0; j < 8; ++j) {
      u[j] = __float_as_uint(fv[j]);
      l[j] = __float_as_uint(fv[j] - __uint_as_float(u[j] & 0xFFFF0000u));
    }
    ABfrag ahi, alo;
    ahi.u[0] = packhi(u[0], u[1]); ahi.u[1] = packhi(u[2], u[3]);
    ahi.u[2] = packhi(u[4], u[5]); ahi.u[3] = packhi(u[6], u[7]);
    alo.u[0] = packhi(l[0], l[1]); alo.u[1] = packhi(l[2], l[3]);
    alo.u[2] = packhi(l[4], l[5]); alo.u[3] = packhi(l[6], l[7]);

    const bf16x8 bhi = *reinterpret_cast<const bf16x8*>(&w1hi[s][lane][0]);
    const bf16x8 blo = *reinterpret_cast<const bf16x8*>(&w1lo[s][lane][0]);

    acc = __builtin_amdgcn_mfma_f32_16x16x32_bf16(ahi.v, bhi, acc, 0, 0, 0);
    acc = __builtin_amdgcn_mfma_f32_16x16x32_bf16(alo.v, bhi, acc, 0, 0, 0);
    acc = __builtin_amdgcn_mfma_f32_16x16x32_bf16(ahi.v, blo, acc, 0, 0, 0);
  }

  // ---------- epilogue: h -> z, store ----------
  const int r0 = (lane >> 4) * 4;
#pragma unroll
  for (int i = 0; i < 4; ++i) {
    float s = fmaxf(acc[i] + bq, 0.f) + tq;
    z[(size_t)(row0 + r0 + i) * zstride + q5] = __cosf(s);
  }
}

// ============================================================
// Kernel O: out[row] = z[row] @ W2 + b2  (unchanged; ~5 us, L3-absorbed)
//   z/out intentionally NOT __restrict__ (aliased fallback).
// ============================================================
#define OTPB 256
#define ORPB 16
#define ONBLOCKS (ROWS_TOTAL / ORPB)  // 2048

__global__ __launch_bounds__(OTPB, 4)
void o_kernel(const float* z, int zstride, const float* __restrict__ W2,
              const float* __restrict__ b2, float* out) {
  const int t   = threadIdx.x;
  const int col = 4 * t;

  float4 w2r[QDIM];
#pragma unroll
  for (int q = 0; q < QDIM; ++q)
    w2r[q] = *reinterpret_cast<const float4*>(W2 + (size_t)q * DDIM + col);
  const float4 bb = *reinterpret_cast<const float4*>(b2 + col);

  const int row0 = blockIdx.x * ORPB;

  const float* zp0 = z + (size_t)row0 * zstride;
  float4 zc0 = *reinterpret_cast<const float4*>(zp0 + 0);
  float4 zc1 = *reinterpret_cast<const float4*>(zp0 + 4);
  float4 zc2 = *reinterpret_cast<const float4*>(zp0 + 8);
  float4 zc3 = *reinterpret_cast<const float4*>(zp0 + 12);

#pragma unroll
  for (int r = 0; r < ORPB; ++r) {
    float4 zn0 = zc0, zn1 = zc1, zn2 = zc2, zn3 = zc3;
    if (r + 1 < ORPB) {
      const float* znp = z + (size_t)(row0 + r + 1) * zstride;
      zn0 = *reinterpret_cast<const float4*>(znp + 0);
      zn1 = *reinterpret_cast<const float4*>(znp + 4);
      zn2 = *reinterpret_cast<const float4*>(znp + 8);
      zn3 = *reinterpret_cast<const float4*>(znp + 12);
    }

    const float zv[16] = {zc0.x, zc0.y, zc0.z, zc0.w,
                          zc1.x, zc1.y, zc1.z, zc1.w,
                          zc2.x, zc2.y, zc2.z, zc2.w,
                          zc3.x, zc3.y, zc3.z, zc3.w};
    float4 acc = bb;
#pragma unroll
    for (int q = 0; q < QDIM; ++q) {
      acc.x = fmaf(zv[q], w2r[q].x, acc.x);
      acc.y = fmaf(zv[q], w2r[q].y, acc.y);
      acc.z = fmaf(zv[q], w2r[q].z, acc.z);
      acc.w = fmaf(zv[q], w2r[q].w, acc.w);
    }
    *reinterpret_cast<float4*>(out + (size_t)(row0 + r) * DDIM + col) = acc;

    zc0 = zn0; zc1 = zn1; zc2 = zn2; zc3 = zn3;
  }
}

extern "C" void kernel_launch(void* const* d_in, const int* in_sizes, int n_in,
                              void* d_out, int out_size, void* d_ws, size_t ws_size,
                              hipStream_t stream) {
  const float* x     = (const float*)d_in[0];
  const float* W1    = (const float*)d_in[1];
  const float* b1    = (const float*)d_in[2];
  const float* theta = (const float*)d_in[3];
  const float* W2    = (const float*)d_in[4];
  const float* b2    = (const float*)d_in[5];
  float* out = (float*)d_out;

  const size_t zbytes = (size_t)ROWS_TOTAL * QDIM * sizeof(float);  // 2 MB
  float* zbuf;
  int zstride;
  if (d_ws != nullptr && ws_size >= zbytes) {
    zbuf = (float*)d_ws;  // compact z in workspace
    zstride = QDIM;
  } else {
    zbuf = out;           // fallback: stash z in out[row][0:16]
    zstride = DDIM;
  }

  z_kernel<<<dim3(ZNBLOCKS), dim3(ZTPB), 0, stream>>>(x, W1, b1, theta, zbuf, zstride);
  o_kernel<<<dim3(ONBLOCKS), dim3(OTPB), 0, stream>>>(zbuf, zstride, W2, b2, out);
}

// Round 5
// 55.404 us; speedup vs baseline: 1.4443x; 1.0096x over previous
//
#include <hip/hip_runtime.h>
#include <math.h>
#include <stdint.h>

// Problem constants: B=8, S=4096, D=1024, Q=16 -> 32768 rows
#define ROWS_TOTAL 32768
#define DDIM 1024
#define QDIM 16

typedef __attribute__((ext_vector_type(8))) short bf16x8;  // 8 bf16 (4 VGPRs)
typedef __attribute__((ext_vector_type(4))) float f32x4;   // 4 f32 acc

union ABfrag { uint32_t u[4]; bf16x8 v; };

// pack the high 16 bits (truncated bf16) of two f32 bit patterns:
// result low ushort = a.hi16 (lower-k element), high ushort = b.hi16
__device__ __forceinline__ uint32_t packhi(uint32_t a, uint32_t b) {
  return __builtin_amdgcn_perm(b, a, 0x07060302u);
}

// ============================================================
// Kernel Z (MFMA): z[row][q] = cos(relu(x[row]@W1 + b1) + theta)
//
// One wave owns 16 rows; K-loop 32 steps of K=32 via
// __builtin_amdgcn_mfma_f32_16x16x32_bf16, f32 accuracy via split-bf16:
//   acc += A_hi*B_hi + A_lo*B_hi + A_hi*B_lo
//
// COALESCING-OPTIMAL k-permutation (this round's change): lane-group
// g = l>>4 owns k-slots {4g..4g+3} U {16+4g..16+4g+3} (j=0..3 -> 4g+j,
// j=4..7 -> 16+4g+j-4) instead of {8g..8g+7}. Per wave-load instruction,
// row r's 4 lane-groups now cover bytes 0..64 CONTIGUOUSLY (one fully
// used 64B line per row per instr; was two half-used lines). A and B
// use the SAME permutation, so the contraction is unchanged.
// C/D layout (m89-verified): lane l holds D[(l>>4)*4+i][l&15].
//
// No barriers after the single staging barrier; depth-6 rotating
// prefetch (12 float4 in flight/lane) -> BW-bound streaming.
// ============================================================
#define ZTPB 256
#define ZWPB 4                      // waves per block
#define ZNBLOCKS (ROWS_TOTAL / (ZWPB * 16))   // 512

__global__ __launch_bounds__(ZTPB, 2)
void z_kernel(const float* __restrict__ x, const float* __restrict__ W1,
              const float* __restrict__ b1, const float* __restrict__ theta,
              float* __restrict__ z, int zstride) {
  const int t    = threadIdx.x;
  const int lane = t & 63;
  const int wid  = t >> 6;

  __shared__ __align__(16) ushort w1hi[32][64][8];  // [kstep][lane][j] 32 KB
  __shared__ __align__(16) ushort w1lo[32][64][8];  // 32 KB

  // ---------- stage W1 as split-bf16 B-fragments (once per block) ----------
  // Thread t owns W1 rows d = 4t..4t+3. With the new k-permutation:
  //   k-within-step = d&31 = 4g + (j&3) + 16*(j>>2)
  //   => g = (d>>2)&3, j = (d&3) + 4*((d>>4)&1)
  // For d = 4t..4t+3: step = t>>3, g = t&3, j0 = 4*((t>>2)&1), j = j0+(d&3).
  {
    const int step = t >> 3;           // d/32
    const int lg   = t & 3;            // g = (d>>2)&3
    const int j0   = ((t >> 2) & 1) * 4;  // 4*((d>>4)&1)
    const float* wp = W1 + (size_t)(4 * t) * QDIM;
    float4 wr[4][4];  // [row r][q-group]
#pragma unroll
    for (int r = 0; r < 4; ++r)
#pragma unroll
      for (int qq = 0; qq < 4; ++qq)
        wr[r][qq] =
            *reinterpret_cast<const float4*>(wp + (size_t)r * QDIM + 4 * qq);

#pragma unroll
    for (int qq = 0; qq < 4; ++qq) {
#pragma unroll
      for (int m = 0; m < 4; ++m) {
        const int q = 4 * qq + m;
        float f[4];
#pragma unroll
        for (int r = 0; r < 4; ++r)
          f[r] = (m == 0) ? wr[r][qq].x
               : (m == 1) ? wr[r][qq].y
               : (m == 2) ? wr[r][qq].z
                          : wr[r][qq].w;
        uint32_t u[4], l[4];
#pragma unroll
        for (int r = 0; r < 4; ++r) {
          u[r] = __float_as_uint(f[r]);
          l[r] = __float_as_uint(f[r] - __uint_as_float(u[r] & 0xFFFF0000u));
        }
        const int ln = lg * 16 + q;
        *reinterpret_cast<uint2*>(&w1hi[step][ln][j0]) =
            make_uint2(packhi(u[0], u[1]), packhi(u[2], u[3]));
        *reinterpret_cast<uint2*>(&w1lo[step][ln][j0]) =
            make_uint2(packhi(l[0], l[1]), packhi(l[2], l[3]));
      }
    }
  }

  // per-lane epilogue constants (issued early, used after the K-loop)
  const int   q5 = lane & 15;
  const float bq = b1[q5];
  const float tq = theta[q5];

  __syncthreads();

  // ---------- main: one 16-row tile per wave ----------
  const int row0 = (blockIdx.x * ZWPB + wid) * 16;
  // lane base: row (lane&15), float offset 4*(lane>>4)  [new permutation]
  const float* xl =
      x + (size_t)(row0 + (lane & 15)) * DDIM + (lane >> 4) * 4;

  // depth-6 rotating prefetch of A (raw f32)
  // pa[s]: floats 32s + 4g + {0..3}    (j = 0..3)
  // pb[s]: floats 32s + 16 + 4g + {0..3} (j = 4..7)
  float4 pa[6], pb[6];
#pragma unroll
  for (int s = 0; s < 6; ++s) {
    pa[s] = *reinterpret_cast<const float4*>(xl + s * 32);
    pb[s] = *reinterpret_cast<const float4*>(xl + s * 32 + 16);
  }

  f32x4 acc = {0.f, 0.f, 0.f, 0.f};

#pragma unroll
  for (int s = 0; s < 32; ++s) {
    const float4 a0 = pa[s % 6];
    const float4 a1 = pb[s % 6];
    if (s + 6 < 32) {
      pa[s % 6] = *reinterpret_cast<const float4*>(xl + (s + 6) * 32);
      pb[s % 6] = *reinterpret_cast<const float4*>(xl + (s + 6) * 32 + 16);
    }

    const float fv[8] = {a0.x, a0.y, a0.z, a0.w, a1.x, a1.y, a1.z, a1.w};
    uint32_t u[8], l[8];
#pragma unroll
    for (int j = 0; j < 8; ++j) {
      u[j] = __float_as_uint(fv[j]);
      l[j] = __float_as_uint(fv[j] - __uint_as_float(u[j] & 0xFFFF0000u));
    }
    ABfrag ahi, alo;
    ahi.u[0] = packhi(u[0], u[1]); ahi.u[1] = packhi(u[2], u[3]);
    ahi.u[2] = packhi(u[4], u[5]); ahi.u[3] = packhi(u[6], u[7]);
    alo.u[0] = packhi(l[0], l[1]); alo.u[1] = packhi(l[2], l[3]);
    alo.u[2] = packhi(l[4], l[5]); alo.u[3] = packhi(l[6], l[7]);

    const bf16x8 bhi = *reinterpret_cast<const bf16x8*>(&w1hi[s][lane][0]);
    const bf16x8 blo = *reinterpret_cast<const bf16x8*>(&w1lo[s][lane][0]);

    acc = __builtin_amdgcn_mfma_f32_16x16x32_bf16(ahi.v, bhi, acc, 0, 0, 0);
    acc = __builtin_amdgcn_mfma_f32_16x16x32_bf16(alo.v, bhi, acc, 0, 0, 0);
    acc = __builtin_amdgcn_mfma_f32_16x16x32_bf16(ahi.v, blo, acc, 0, 0, 0);
  }

  // ---------- epilogue: h -> z, store ----------
  const int r0 = (lane >> 4) * 4;
#pragma unroll
  for (int i = 0; i < 4; ++i) {
    float s = fmaxf(acc[i] + bq, 0.f) + tq;
    z[(size_t)(row0 + r0 + i) * zstride + q5] = __cosf(s);
  }
}

// ============================================================
// Kernel O: out[row] = z[row] @ W2 + b2  (unchanged this round, so any
//   delta is attributable to z). z/out intentionally NOT __restrict__.
// ============================================================
#define OTPB 256
#define ORPB 16
#define ONBLOCKS (ROWS_TOTAL / ORPB)  // 2048

__global__ __launch_bounds__(OTPB, 4)
void o_kernel(const float* z, int zstride, const float* __restrict__ W2,
              const float* __restrict__ b2, float* out) {
  const int t   = threadIdx.x;
  const int col = 4 * t;

  float4 w2r[QDIM];
#pragma unroll
  for (int q = 0; q < QDIM; ++q)
    w2r[q] = *reinterpret_cast<const float4*>(W2 + (size_t)q * DDIM + col);
  const float4 bb = *reinterpret_cast<const float4*>(b2 + col);

  const int row0 = blockIdx.x * ORPB;

  const float* zp0 = z + (size_t)row0 * zstride;
  float4 zc0 = *reinterpret_cast<const float4*>(zp0 + 0);
  float4 zc1 = *reinterpret_cast<const float4*>(zp0 + 4);
  float4 zc2 = *reinterpret_cast<const float4*>(zp0 + 8);
  float4 zc3 = *reinterpret_cast<const float4*>(zp0 + 12);

#pragma unroll
  for (int r = 0; r < ORPB; ++r) {
    float4 zn0 = zc0, zn1 = zc1, zn2 = zc2, zn3 = zc3;
    if (r + 1 < ORPB) {
      const float* znp = z + (size_t)(row0 + r + 1) * zstride;
      zn0 = *reinterpret_cast<const float4*>(znp + 0);
      zn1 = *reinterpret_cast<const float4*>(znp + 4);
      zn2 = *reinterpret_cast<const float4*>(znp + 8);
      zn3 = *reinterpret_cast<const float4*>(znp + 12);
    }

    const float zv[16] = {zc0.x, zc0.y, zc0.z, zc0.w,
                          zc1.x, zc1.y, zc1.z, zc1.w,
                          zc2.x, zc2.y, zc2.z, zc2.w,
                          zc3.x, zc3.y, zc3.z, zc3.w};
    float4 acc = bb;
#pragma unroll
    for (int q = 0; q < QDIM; ++q) {
      acc.x = fmaf(zv[q], w2r[q].x, acc.x);
      acc.y = fmaf(zv[q], w2r[q].y, acc.y);
      acc.z = fmaf(zv[q], w2r[q].z, acc.z);
      acc.w = fmaf(zv[q], w2r[q].w, acc.w);
    }
    *reinterpret_cast<float4*>(out + (size_t)(row0 + r) * DDIM + col) = acc;

    zc0 = zn0; zc1 = zn1; zc2 = zn2; zc3 = zn3;
  }
}

extern "C" void kernel_launch(void* const* d_in, const int* in_sizes, int n_in,
                              void* d_out, int out_size, void* d_ws, size_t ws_size,
                              hipStream_t stream) {
  const float* x     = (const float*)d_in[0];
  const float* W1    = (const float*)d_in[1];
  const float* b1    = (const float*)d_in[2];
  const float* theta = (const float*)d_in[3];
  const float* W2    = (const float*)d_in[4];
  const float* b2    = (const float*)d_in[5];
  float* out = (float*)d_out;

  const size_t zbytes = (size_t)ROWS_TOTAL * QDIM * sizeof(float);  // 2 MB
  float* zbuf;
  int zstride;
  if (d_ws != nullptr && ws_size >= zbytes) {
    zbuf = (float*)d_ws;  // compact z in workspace
    zstride = QDIM;
  } else {
    zbuf = out;           // fallback: stash z in out[row][0:16]
    zstride = DDIM;
  }

  z_kernel<<<dim3(ZNBLOCKS), dim3(ZTPB), 0, stream>>>(x, W1, b1, theta, zbuf, zstride);
  o_kernel<<<dim3(ONBLOCKS), dim3(OTPB), 0, stream>>>(zbuf, zstride, W2, b2, out);
}